// Round 9
// baseline (278.265 us; speedup 1.0000x reference)
//
#include <hip/hip_runtime.h>
#include <hip/hip_bf16.h>

#define T_SEQ 2048
#define EMB   128
#define H     16
#define BATCH 8
#define BQ    64          // query rows per attention block (4 waves x 16 rows)
#define MAXP  8           // chunks per row (CHUNK=256)
// Q pre-scale: 1/sqrt(16) * log2(e)  -> scores come out in log2 domain
#define QSCALE 0.360673760222241f

// exp2 via the clang builtin (proven r8); __exp2f clashes with glibc macro.
#define EXP2F(x) __builtin_amdgcn_exp2f(x)

typedef short short8_t __attribute__((ext_vector_type(8)));  // 8 bf16
typedef float f32x4    __attribute__((ext_vector_type(4)));  // MFMA C/D frag

__device__ __forceinline__ unsigned short f2bf(float f) {
    __hip_bfloat16 h = __float2bfloat16(f);
    return *reinterpret_cast<unsigned short*>(&h);
}

// ---------------------------------------------------------------------------
// Kernel 1: QKV projection via MFMA (r8-proven). Also zeroes the split-K
// counters used by the fused attention kernel (stream-ordered before it).
// ---------------------------------------------------------------------------
__global__ __launch_bounds__(256) void qkv_kernel(
    const float* __restrict__ x,
    const float* __restrict__ Wq,
    const float* __restrict__ Wk,
    const float* __restrict__ Wv,
    unsigned short* __restrict__ Qbf,
    unsigned short* __restrict__ Kbf,
    unsigned short* __restrict__ Vt,
    int* __restrict__ cnt)
{
    __shared__ unsigned short Wt[3][16][136];

    const int tid = threadIdx.x;
    if (blockIdx.x == 0) cnt[tid] = 0;          // 256 counters (b,qt)

#pragma unroll
    for (int p = 0; p < 6; ++p) {
        const int idx4 = tid + p * 256;
        const int flat = idx4 * 4;
        const int mm   = flat >> 11;
        const int rem  = flat & 2047;
        const int d    = rem >> 4;
        const int c0   = rem & 15;
        const float* Wm = (mm == 0) ? Wq : (mm == 1) ? Wk : Wv;
        float4 w = *reinterpret_cast<const float4*>(Wm + rem);
        Wt[mm][c0    ][d] = f2bf(w.x);
        Wt[mm][c0 + 1][d] = f2bf(w.y);
        Wt[mm][c0 + 2][d] = f2bf(w.z);
        Wt[mm][c0 + 3][d] = f2bf(w.w);
    }
    __syncthreads();

    const int wv   = tid >> 6;
    const int lane = tid & 63;
    const int q    = lane >> 4;
    const int n    = lane & 15;
    const int row0 = blockIdx.x * 64 + wv * 16;
    const float* xr = x + (size_t)(row0 + n) * EMB;

    f32x4 aq = {0,0,0,0}, ak = {0,0,0,0}, av = {0,0,0,0};
#pragma unroll
    for (int t = 0; t < 4; ++t) {
        const int k0 = t * 32 + q * 8;
        float4 xa = *reinterpret_cast<const float4*>(xr + k0);
        float4 xb = *reinterpret_cast<const float4*>(xr + k0 + 4);
        union { unsigned short s[8]; short8_t v; } xf;
        xf.s[0]=f2bf(xa.x); xf.s[1]=f2bf(xa.y); xf.s[2]=f2bf(xa.z); xf.s[3]=f2bf(xa.w);
        xf.s[4]=f2bf(xb.x); xf.s[5]=f2bf(xb.y); xf.s[6]=f2bf(xb.z); xf.s[7]=f2bf(xb.w);
        short8_t wqf = *reinterpret_cast<const short8_t*>(&Wt[0][n][k0]);
        short8_t wkf = *reinterpret_cast<const short8_t*>(&Wt[1][n][k0]);
        short8_t wvf = *reinterpret_cast<const short8_t*>(&Wt[2][n][k0]);
        aq = __builtin_amdgcn_mfma_f32_16x16x32_bf16(xf.v, wqf, aq, 0, 0, 0);
        ak = __builtin_amdgcn_mfma_f32_16x16x32_bf16(xf.v, wkf, ak, 0, 0, 0);
        av = __builtin_amdgcn_mfma_f32_16x16x32_bf16(xf.v, wvf, av, 0, 0, 0);
    }

    const int grow = row0 + q * 4;
    const int b    = grow >> 11;
    const int ib0  = grow & 2047;
#pragma unroll
    for (int r = 0; r < 4; ++r) {
        Qbf[(size_t)(grow + r) * H + n] = f2bf(aq[r] * QSCALE);
        Kbf[(size_t)(grow + r) * H + n] = f2bf(ak[r]);
    }
    union { unsigned short s[4]; unsigned long long u; } vp;
    vp.s[0]=f2bf(av[0]); vp.s[1]=f2bf(av[1]); vp.s[2]=f2bf(av[2]); vp.s[3]=f2bf(av[3]);
    *reinterpret_cast<unsigned long long*>(
        Vt + ((size_t)b * H + n) * T_SEQ + ib0) = vp.u;
}

// ---------------------------------------------------------------------------
// Kernel 2: fused flash attention + split-K combine.
// Grid (144, 8): x enumerates exactly the valid (qt,chunk) pairs (heavy
// first), y = batch. 4 independent waves (16 Q-rows each), no barriers in
// the main loop. Iterations process 128 keys: 8 S-MFMAs (batched K loads),
// ONE softmax pass (2 shuffles: max only; l kept per-quad, summed once at
// end), P->Pbuf[wave][row][...] (b64 writes, b128 reads), 4 PV-MFMAs.
// Epilogue: write unnormalized partial; last block per (b,qt) combines all
// chunks in fixed order (deterministic) and writes the output.
// ---------------------------------------------------------------------------
__global__ __launch_bounds__(256) void attn_fused(
    const unsigned short* __restrict__ Qbf,
    const unsigned short* __restrict__ Kbf,
    const unsigned short* __restrict__ Vt,
    float* __restrict__ P2,
    int* __restrict__ cnt,
    float* __restrict__ out)
{
    __shared__ unsigned int Pbuf[4][16][136];   // 34.8 KB
    __shared__ int sCombine;

    // Decode compact (qt, cch): group g has 4 q-tiles x (g+1) chunks,
    // cumulative start 2g(g+1); heavy groups first.
    const int b = blockIdx.y;
    const int r = 143 - blockIdx.x;
    int g = 0;
    while (r >= 2 * (g + 1) * (g + 2)) ++g;     // g in 0..7
    const int idx = r - 2 * g * (g + 1);
    const int qq  = idx / (g + 1);
    const int qt  = 4 * g + qq;
    const int cch = idx - qq * (g + 1);
    const int nc  = g + 1;                      // chunks for this q-tile

    const int i0   = qt << 6;
    const int kbeg = cch << 8;

    const int tid  = threadIdx.x;
    const int wv   = tid >> 6;
    const int lane = tid & 63;
    const int q    = lane >> 4;
    const int n    = lane & 15;
    const int wrow0 = i0 + wv * 16;
    const int irow  = wrow0 + n;
    const int kend  = min(kbeg + 256, wrow0 + 16);
    const int nit   = (kend - kbeg + 127) >> 7; // 128-key iterations (1 or 2)

    const unsigned short* Qp = Qbf + (size_t)b * T_SEQ * H;
    const unsigned short* Kp = Kbf + (size_t)b * T_SEQ * H;
    const unsigned short* vrow = Vt + (size_t)b * H * T_SEQ + (size_t)n * T_SEQ;

    short8_t qf = {0,0,0,0,0,0,0,0};
    if (q < 2)
        qf = *reinterpret_cast<const short8_t*>(Qp + (size_t)irow * H + q * 8);

    f32x4 acc = {0.f, 0.f, 0.f, 0.f};
    float m = -1e30f, l = 0.f;                  // l is a per-quad partial

    for (int it = 0; it < nit; ++it) {
        const int j0   = kbeg + (it << 7);
        const int base = (it & 1) << 6;         // Pbuf parity (WAR-free)

        // 8 S-MFMAs, K loads batched for memory-level parallelism.
        f32x4 S[8];
#pragma unroll
        for (int s = 0; s < 8; ++s) {
            short8_t kf = {0,0,0,0,0,0,0,0};
            if (q < 2)
                kf = *reinterpret_cast<const short8_t*>(
                        Kp + (size_t)(j0 + s * 16 + n) * H + q * 8);
            f32x4 z = {0.f, 0.f, 0.f, 0.f};
            S[s] = __builtin_amdgcn_mfma_f32_16x16x32_bf16(kf, qf, z, 0, 0, 0);
        }
        // V fragments early (hide latency under softmax).
        short8_t vf[4];
#pragma unroll
        for (int h = 0; h < 4; ++h)
            vf[h] = *reinterpret_cast<const short8_t*>(vrow + j0 + h * 32 + q * 8);

        // Mask (only when the 128-key span can straddle any row) + max.
        float tm = -1e30f;
        if (j0 + 127 > wrow0) {
#pragma unroll
            for (int s = 0; s < 8; ++s) {
                const int kb = j0 + s * 16 + q * 4;
#pragma unroll
                for (int rr = 0; rr < 4; ++rr) {
                    float v = (kb + rr <= irow) ? S[s][rr] : -1e30f;
                    S[s][rr] = v;
                    tm = fmaxf(tm, v);
                }
            }
        } else {
#pragma unroll
            for (int s = 0; s < 8; ++s)
                tm = fmaxf(tm, fmaxf(fmaxf(S[s][0], S[s][1]),
                                     fmaxf(S[s][2], S[s][3])));
        }
        tm = fmaxf(tm, __shfl_xor(tm, 16));
        tm = fmaxf(tm, __shfl_xor(tm, 32));
        const float mn    = fmaxf(m, tm);
        const float alpha = EXP2F(m - mn);
        m = mn;

        // exp2, per-quad partial sum, pack P^T (bf16) into Pbuf.
        float ps = 0.f;
#pragma unroll
        for (int s = 0; s < 8; ++s) {
            float e0 = EXP2F(S[s][0] - mn);
            float e1 = EXP2F(S[s][1] - mn);
            float e2 = EXP2F(S[s][2] - mn);
            float e3 = EXP2F(S[s][3] - mn);
            ps += (e0 + e1) + (e2 + e3);
            unsigned int b0 = __builtin_bit_cast(unsigned int, e0);
            unsigned int b1 = __builtin_bit_cast(unsigned int, e1);
            unsigned int b2 = __builtin_bit_cast(unsigned int, e2);
            unsigned int b3 = __builtin_bit_cast(unsigned int, e3);
            unsigned long long pw =
                (unsigned long long)((b1 & 0xffff0000u) | (b0 >> 16)) |
                ((unsigned long long)((b3 & 0xffff0000u) | (b2 >> 16)) << 32);
            *reinterpret_cast<unsigned long long*>(
                &Pbuf[wv][n][base + 8 * s + 2 * q]) = pw;
        }
        l = l * alpha + ps;
        acc[0] *= alpha; acc[1] *= alpha; acc[2] *= alpha; acc[3] *= alpha;

        // PV: O^T += V^T · P^T (4 MFMAs, b128 Pbuf reads).
#pragma unroll
        for (int h = 0; h < 4; ++h) {
            uint4 p4 = *reinterpret_cast<const uint4*>(
                    &Pbuf[wv][n][base + 16 * h + 4 * q]);
            union { uint4 u; short8_t v; } pu; pu.u = p4;
            acc = __builtin_amdgcn_mfma_f32_16x16x32_bf16(vf[h], pu.v, acc, 0, 0, 0);
        }
    }

    // Cross-quad l sum (once), then write unnormalized partial.
    l += __shfl_xor(l, 16);
    l += __shfl_xor(l, 32);

    float* pp = P2 + ((size_t)(b * T_SEQ + irow) * MAXP + cch) * 18;
    float2 r01; r01.x = acc[0]; r01.y = acc[1];
    float2 r23; r23.x = acc[2]; r23.y = acc[3];
    *reinterpret_cast<float2*>(pp + q * 4)     = r01;
    *reinterpret_cast<float2*>(pp + q * 4 + 2) = r23;
    if (q == 0) { pp[16] = m; pp[17] = l; }

    // ---- split-K combine: last block per (b,qt) merges all chunks ----
    __threadfence();                            // release partials (device)
    __syncthreads();
    if (tid == 0) {
        int old = atomicAdd(&cnt[b * 32 + qt], 1);
        sCombine = (old == nc - 1);
    }
    __syncthreads();
    if (!sCombine) return;
    __threadfence();                            // acquire others' partials

#pragma unroll
    for (int rr = 0; rr < 4; ++rr) {
        const int gidx = tid + rr * 256;        // 0..1023 = 64 rows x 16 dims
        const int row  = gidx >> 4;
        const int d    = gidx & 15;
        const float* basep = P2 + (size_t)(b * T_SEQ + i0 + row) * (MAXP * 18);
        float M = -1e30f;
        for (int p = 0; p < nc; ++p) M = fmaxf(M, basep[p * 18 + 16]);
        float L = 0.f, o = 0.f;
        for (int p = 0; p < nc; ++p) {          // fixed order: deterministic
            const float wgt = EXP2F(basep[p * 18 + 16] - M);
            L += wgt * basep[p * 18 + 17];
            o += wgt * basep[p * 18 + d];
        }
        out[(size_t)(b * T_SEQ + i0 + row) * H + d] = o / L;
    }
}

// ---------------------------------------------------------------------------
extern "C" void kernel_launch(void* const* d_in, const int* in_sizes, int n_in,
                              void* d_out, int out_size, void* d_ws, size_t ws_size,
                              hipStream_t stream)
{
    const float* x  = (const float*)d_in[0];
    const float* Wq = (const float*)d_in[1];
    const float* Wk = (const float*)d_in[2];
    const float* Wv = (const float*)d_in[3];
    float* out = (float*)d_out;

    const size_t NE = (size_t)BATCH * T_SEQ * H;      // 262144 elems per buf
    unsigned short* Qbf = (unsigned short*)d_ws;
    unsigned short* Kbf = Qbf + NE;
    unsigned short* Vt  = Kbf + NE;
    float* P2 = (float*)(Vt + NE);                    // 16384*8*18 floats
    int*   cnt = (int*)(P2 + (size_t)BATCH * T_SEQ * MAXP * 18);

    qkv_kernel<<<BATCH * T_SEQ / 64, 256, 0, stream>>>(
        x, Wq, Wk, Wv, Qbf, Kbf, Vt, cnt);
    attn_fused<<<dim3(144, BATCH), 256, 0, stream>>>(
        Qbf, Kbf, Vt, P2, cnt, out);
}

// Round 10
// 88.186 us; speedup vs baseline: 3.1554x; 3.1554x over previous
//
#include <hip/hip_runtime.h>
#include <hip/hip_bf16.h>

#define T_SEQ 2048
#define EMB   128
#define H     16
#define BATCH 8
#define MAXP  16          // chunks per row (CHUNK=128)
// Q pre-scale: 1/sqrt(16) * log2(e)  -> scores come out in log2 domain
#define QSCALE 0.360673760222241f

// exp2 via the clang builtin (r8-proven); __exp2f clashes with glibc macro.
#define EXP2F(x) __builtin_amdgcn_exp2f(x)

typedef short short8_t __attribute__((ext_vector_type(8)));  // 8 bf16
typedef float f32x4    __attribute__((ext_vector_type(4)));  // MFMA C/D frag

__device__ __forceinline__ unsigned short f2bf(float f) {
    __hip_bfloat16 h = __float2bfloat16(f);
    return *reinterpret_cast<unsigned short*>(&h);
}

// ---------------------------------------------------------------------------
// Kernel 1: QKV projection via MFMA (r8-proven structure).
// ---------------------------------------------------------------------------
__global__ __launch_bounds__(256) void qkv_kernel(
    const float* __restrict__ x,
    const float* __restrict__ Wq,
    const float* __restrict__ Wk,
    const float* __restrict__ Wv,
    unsigned short* __restrict__ Qbf,
    unsigned short* __restrict__ Kbf,
    unsigned short* __restrict__ Vt)
{
    __shared__ unsigned short Wt[3][16][136];

    const int tid = threadIdx.x;
#pragma unroll
    for (int p = 0; p < 6; ++p) {
        const int idx4 = tid + p * 256;
        const int flat = idx4 * 4;
        const int mm   = flat >> 11;
        const int rem  = flat & 2047;
        const int d    = rem >> 4;
        const int c0   = rem & 15;
        const float* Wm = (mm == 0) ? Wq : (mm == 1) ? Wk : Wv;
        float4 w = *reinterpret_cast<const float4*>(Wm + rem);
        Wt[mm][c0    ][d] = f2bf(w.x);
        Wt[mm][c0 + 1][d] = f2bf(w.y);
        Wt[mm][c0 + 2][d] = f2bf(w.z);
        Wt[mm][c0 + 3][d] = f2bf(w.w);
    }
    __syncthreads();

    const int wv   = tid >> 6;
    const int lane = tid & 63;
    const int q    = lane >> 4;
    const int n    = lane & 15;
    const int row0 = blockIdx.x * 64 + wv * 16;
    const float* xr = x + (size_t)(row0 + n) * EMB;

    f32x4 aq = {0,0,0,0}, ak = {0,0,0,0}, av = {0,0,0,0};
#pragma unroll
    for (int t = 0; t < 4; ++t) {
        const int k0 = t * 32 + q * 8;
        float4 xa = *reinterpret_cast<const float4*>(xr + k0);
        float4 xb = *reinterpret_cast<const float4*>(xr + k0 + 4);
        union { unsigned short s[8]; short8_t v; } xf;
        xf.s[0]=f2bf(xa.x); xf.s[1]=f2bf(xa.y); xf.s[2]=f2bf(xa.z); xf.s[3]=f2bf(xa.w);
        xf.s[4]=f2bf(xb.x); xf.s[5]=f2bf(xb.y); xf.s[6]=f2bf(xb.z); xf.s[7]=f2bf(xb.w);
        short8_t wqf = *reinterpret_cast<const short8_t*>(&Wt[0][n][k0]);
        short8_t wkf = *reinterpret_cast<const short8_t*>(&Wt[1][n][k0]);
        short8_t wvf = *reinterpret_cast<const short8_t*>(&Wt[2][n][k0]);
        aq = __builtin_amdgcn_mfma_f32_16x16x32_bf16(xf.v, wqf, aq, 0, 0, 0);
        ak = __builtin_amdgcn_mfma_f32_16x16x32_bf16(xf.v, wkf, ak, 0, 0, 0);
        av = __builtin_amdgcn_mfma_f32_16x16x32_bf16(xf.v, wvf, av, 0, 0, 0);
    }

    const int grow = row0 + q * 4;
    const int b    = grow >> 11;
    const int ib0  = grow & 2047;
#pragma unroll
    for (int r = 0; r < 4; ++r) {
        Qbf[(size_t)(grow + r) * H + n] = f2bf(aq[r] * QSCALE);
        Kbf[(size_t)(grow + r) * H + n] = f2bf(ak[r]);
    }
    union { unsigned short s[4]; unsigned long long u; } vp;
    vp.s[0]=f2bf(av[0]); vp.s[1]=f2bf(av[1]); vp.s[2]=f2bf(av[2]); vp.s[3]=f2bf(av[3]);
    *reinterpret_cast<unsigned long long*>(
        Vt + ((size_t)b * H + n) * T_SEQ + ib0) = vp.u;
}

// ---------------------------------------------------------------------------
// Kernel 2a: single-shot flash attention chunk. Grid (272, 8): x enumerates
// exactly the valid (qt, cch) pairs (cch <= qt/2), y = batch. 4 independent
// waves (16 Q-rows each over the same 128 keys); NO loop, NO barriers, NO
// online-softmax carry. Straight line:
//   12 global loads -> 8 S-MFMAs -> mask/max (2 shuffles) -> exp2 ->
//   LDS transpose (b64 w / b128 r) -> 4 PV-MFMAs -> partial (acc,m,l).
// Every wave provably satisfies wrow0 >= kbeg (both 16-aligned vs 128-
// aligned with kbeg <= i0), so all waves do full useful work and every
// row's max is finite.
// ---------------------------------------------------------------------------
__global__ __launch_bounds__(256) void attn_phase1(
    const unsigned short* __restrict__ Qbf,
    const unsigned short* __restrict__ Kbf,
    const unsigned short* __restrict__ Vt,
    float* __restrict__ P2)
{
    __shared__ unsigned int Pbuf[4][16][68];   // 17.4 KB; stride 68: balanced

    // Decode (qt, cch): qt has (qt>>1)+1 chunks; 272 pairs per batch.
    int r = blockIdx.x;
    int qt = 0;
    while (r >= (qt >> 1) + 1) { r -= (qt >> 1) + 1; ++qt; }
    const int cch  = r;
    const int b    = blockIdx.y;
    const int i0   = qt << 6;
    const int j0   = cch << 7;                 // chunk base (<= i0, in-bounds)

    const int tid  = threadIdx.x;
    const int wv   = tid >> 6;
    const int lane = tid & 63;
    const int q    = lane >> 4;
    const int n    = lane & 15;
    const int wrow0 = i0 + wv * 16;
    const int irow  = wrow0 + n;

    const unsigned short* Qp = Qbf + (size_t)b * T_SEQ * H;
    const unsigned short* Kp = Kbf + (size_t)b * T_SEQ * H;
    const unsigned short* vrow = Vt + (size_t)b * H * T_SEQ + (size_t)n * T_SEQ;

    short8_t qf = {0,0,0,0,0,0,0,0};
    if (q < 2)
        qf = *reinterpret_cast<const short8_t*>(Qp + (size_t)irow * H + q * 8);

    // 8 S-MFMAs; K loads batched (full memory-level parallelism).
    f32x4 S[8];
#pragma unroll
    for (int s = 0; s < 8; ++s) {
        short8_t kf = {0,0,0,0,0,0,0,0};
        if (q < 2)
            kf = *reinterpret_cast<const short8_t*>(
                    Kp + (size_t)(j0 + s * 16 + n) * H + q * 8);
        f32x4 z = {0.f, 0.f, 0.f, 0.f};
        S[s] = __builtin_amdgcn_mfma_f32_16x16x32_bf16(kf, qf, z, 0, 0, 0);
    }
    // V fragments issued early (consumed only after softmax).
    short8_t vf[4];
#pragma unroll
    for (int h = 0; h < 4; ++h)
        vf[h] = *reinterpret_cast<const short8_t*>(vrow + j0 + h * 32 + q * 8);

    // Causal mask only for the diagonal chunk (wave-uniform test) + row max.
    float tm = -1e30f;
    if (j0 + 127 > wrow0) {
#pragma unroll
        for (int s = 0; s < 8; ++s) {
            const int kb = j0 + s * 16 + q * 4;
#pragma unroll
            for (int rr = 0; rr < 4; ++rr) {
                float v = (kb + rr <= irow) ? S[s][rr] : -1e30f;
                S[s][rr] = v;
                tm = fmaxf(tm, v);
            }
        }
    } else {
#pragma unroll
        for (int s = 0; s < 8; ++s)
            tm = fmaxf(tm, fmaxf(fmaxf(S[s][0], S[s][1]),
                                 fmaxf(S[s][2], S[s][3])));
    }
    tm = fmaxf(tm, __shfl_xor(tm, 16));
    tm = fmaxf(tm, __shfl_xor(tm, 32));
    const float m = tm;                        // finite for every row

    // exp2 (log2-domain scores), per-quad partial sum, pack P^T into LDS.
    float l = 0.f;
#pragma unroll
    for (int s = 0; s < 8; ++s) {
        float e0 = EXP2F(S[s][0] - m);
        float e1 = EXP2F(S[s][1] - m);
        float e2 = EXP2F(S[s][2] - m);
        float e3 = EXP2F(S[s][3] - m);
        l += (e0 + e1) + (e2 + e3);
        unsigned int b0 = __builtin_bit_cast(unsigned int, e0);
        unsigned int b1 = __builtin_bit_cast(unsigned int, e1);
        unsigned int b2 = __builtin_bit_cast(unsigned int, e2);
        unsigned int b3 = __builtin_bit_cast(unsigned int, e3);
        unsigned long long pw =
            (unsigned long long)((b1 & 0xffff0000u) | (b0 >> 16)) |
            ((unsigned long long)((b3 & 0xffff0000u) | (b2 >> 16)) << 32);
        *reinterpret_cast<unsigned long long*>(&Pbuf[wv][n][8 * s + 2 * q]) = pw;
    }

    // PV: O^T = V^T · P^T (4 MFMAs, b128 Pbuf reads; same-wave data only).
    f32x4 acc = {0.f, 0.f, 0.f, 0.f};
#pragma unroll
    for (int h = 0; h < 4; ++h) {
        uint4 p4 = *reinterpret_cast<const uint4*>(&Pbuf[wv][n][16 * h + 4 * q]);
        union { uint4 u; short8_t v; } pu; pu.u = p4;
        acc = __builtin_amdgcn_mfma_f32_16x16x32_bf16(vf[h], pu.v, acc, 0, 0, 0);
    }

    // Cross-quad l sum (once), then write unnormalized partial [acc, m, l].
    l += __shfl_xor(l, 16);
    l += __shfl_xor(l, 32);

    float* pp = P2 + ((size_t)(b * T_SEQ + irow) * MAXP + cch) * 18;
    float2 r01; r01.x = acc[0]; r01.y = acc[1];
    float2 r23; r23.x = acc[2]; r23.y = acc[3];
    *reinterpret_cast<float2*>(pp + q * 4)     = r01;
    *reinterpret_cast<float2*>(pp + q * 4 + 2) = r23;
    if (q == 0) { pp[16] = m; pp[17] = l; }
}

// ---------------------------------------------------------------------------
// Kernel 2b: combine partials (log2 domain). One thread per (row, dim).
// Kernel boundary provides cross-XCD visibility of P2 (r9 lesson: never
// use in-kernel device fences for this on gfx950).
// ---------------------------------------------------------------------------
__global__ __launch_bounds__(256) void attn_phase2(
    const float* __restrict__ P2, float* __restrict__ out)
{
    const int gid = blockIdx.x * 256 + threadIdx.x;
    const int row = gid >> 4;
    const int d   = gid & 15;
    const int ib  = row & (T_SEQ - 1);
    const int nc  = (ib >> 7) + 1;             // 128-key chunks this row used
    const float* base = P2 + (size_t)row * (MAXP * 18);

    float M = -1e30f;
    for (int p = 0; p < nc; ++p) M = fmaxf(M, base[p * 18 + 16]);
    float L = 0.f, o = 0.f;
    for (int p = 0; p < nc; ++p) {
        const float wgt = EXP2F(base[p * 18 + 16] - M);
        L += wgt * base[p * 18 + 17];
        o += wgt * base[p * 18 + d];
    }
    out[gid] = o / L;
}

// ---------------------------------------------------------------------------
extern "C" void kernel_launch(void* const* d_in, const int* in_sizes, int n_in,
                              void* d_out, int out_size, void* d_ws, size_t ws_size,
                              hipStream_t stream)
{
    const float* x  = (const float*)d_in[0];
    const float* Wq = (const float*)d_in[1];
    const float* Wk = (const float*)d_in[2];
    const float* Wv = (const float*)d_in[3];
    float* out = (float*)d_out;

    const size_t NE = (size_t)BATCH * T_SEQ * H;      // 262144 elems per buf
    unsigned short* Qbf = (unsigned short*)d_ws;
    unsigned short* Kbf = Qbf + NE;
    unsigned short* Vt  = Kbf + NE;
    float* P2 = (float*)(Vt + NE);                    // 16384*16*18 floats

    qkv_kernel<<<BATCH * T_SEQ / 64, 256, 0, stream>>>(
        x, Wq, Wk, Wv, Qbf, Kbf, Vt);
    attn_phase1<<<dim3(272, BATCH), 256, 0, stream>>>(Qbf, Kbf, Vt, P2);
    attn_phase2<<<(int)(NE / 256), 256, 0, stream>>>(P2, out);
}

// Round 11
// 85.325 us; speedup vs baseline: 3.2613x; 1.0335x over previous
//
#include <hip/hip_runtime.h>
#include <hip/hip_bf16.h>

#define T_SEQ 2048
#define EMB   128
#define H     16
#define BATCH 8
#define MAXP  16          // chunks per row (CHUNK=128)
#define VSTR  2064        // Vt row stride (elems): 4128 B, NOT a power of 2
// Q pre-scale: 1/sqrt(16) * log2(e)  -> scores come out in log2 domain
#define QSCALE 0.360673760222241f

// exp2 via the clang builtin (r8-proven); __exp2f clashes with glibc macro.
#define EXP2F(x) __builtin_amdgcn_exp2f(x)

typedef short short8_t __attribute__((ext_vector_type(8)));  // 8 bf16
typedef float f32x4    __attribute__((ext_vector_type(4)));  // MFMA C/D frag

__device__ __forceinline__ unsigned short f2bf(float f) {
    __hip_bfloat16 h = __float2bfloat16(f);
    return *reinterpret_cast<unsigned short*>(&h);
}

// ---------------------------------------------------------------------------
// Kernel 1: QKV projection via MFMA (r8-proven structure). Vt rows padded
// to VSTR elems to break the 4 KB power-of-2 stride aliasing (r11).
// ---------------------------------------------------------------------------
__global__ __launch_bounds__(256) void qkv_kernel(
    const float* __restrict__ x,
    const float* __restrict__ Wq,
    const float* __restrict__ Wk,
    const float* __restrict__ Wv,
    unsigned short* __restrict__ Qbf,
    unsigned short* __restrict__ Kbf,
    unsigned short* __restrict__ Vt)
{
    __shared__ unsigned short Wt[3][16][136];

    const int tid = threadIdx.x;
#pragma unroll
    for (int p = 0; p < 6; ++p) {
        const int idx4 = tid + p * 256;
        const int flat = idx4 * 4;
        const int mm   = flat >> 11;
        const int rem  = flat & 2047;
        const int d    = rem >> 4;
        const int c0   = rem & 15;
        const float* Wm = (mm == 0) ? Wq : (mm == 1) ? Wk : Wv;
        float4 w = *reinterpret_cast<const float4*>(Wm + rem);
        Wt[mm][c0    ][d] = f2bf(w.x);
        Wt[mm][c0 + 1][d] = f2bf(w.y);
        Wt[mm][c0 + 2][d] = f2bf(w.z);
        Wt[mm][c0 + 3][d] = f2bf(w.w);
    }
    __syncthreads();

    const int wv   = tid >> 6;
    const int lane = tid & 63;
    const int q    = lane >> 4;
    const int n    = lane & 15;
    const int row0 = blockIdx.x * 64 + wv * 16;
    const float* xr = x + (size_t)(row0 + n) * EMB;

    f32x4 aq = {0,0,0,0}, ak = {0,0,0,0}, av = {0,0,0,0};
#pragma unroll
    for (int t = 0; t < 4; ++t) {
        const int k0 = t * 32 + q * 8;
        float4 xa = *reinterpret_cast<const float4*>(xr + k0);
        float4 xb = *reinterpret_cast<const float4*>(xr + k0 + 4);
        union { unsigned short s[8]; short8_t v; } xf;
        xf.s[0]=f2bf(xa.x); xf.s[1]=f2bf(xa.y); xf.s[2]=f2bf(xa.z); xf.s[3]=f2bf(xa.w);
        xf.s[4]=f2bf(xb.x); xf.s[5]=f2bf(xb.y); xf.s[6]=f2bf(xb.z); xf.s[7]=f2bf(xb.w);
        short8_t wqf = *reinterpret_cast<const short8_t*>(&Wt[0][n][k0]);
        short8_t wkf = *reinterpret_cast<const short8_t*>(&Wt[1][n][k0]);
        short8_t wvf = *reinterpret_cast<const short8_t*>(&Wt[2][n][k0]);
        aq = __builtin_amdgcn_mfma_f32_16x16x32_bf16(xf.v, wqf, aq, 0, 0, 0);
        ak = __builtin_amdgcn_mfma_f32_16x16x32_bf16(xf.v, wkf, ak, 0, 0, 0);
        av = __builtin_amdgcn_mfma_f32_16x16x32_bf16(xf.v, wvf, av, 0, 0, 0);
    }

    const int grow = row0 + q * 4;
    const int b    = grow >> 11;
    const int ib0  = grow & 2047;
#pragma unroll
    for (int r = 0; r < 4; ++r) {
        Qbf[(size_t)(grow + r) * H + n] = f2bf(aq[r] * QSCALE);
        Kbf[(size_t)(grow + r) * H + n] = f2bf(ak[r]);
    }
    union { unsigned short s[4]; unsigned long long u; } vp;
    vp.s[0]=f2bf(av[0]); vp.s[1]=f2bf(av[1]); vp.s[2]=f2bf(av[2]); vp.s[3]=f2bf(av[3]);
    *reinterpret_cast<unsigned long long*>(
        Vt + ((size_t)b * H + n) * VSTR + ib0) = vp.u;
}

// ---------------------------------------------------------------------------
// Kernel 2a: single-shot flash attention chunk (r10-proven). Grid (272, 8).
// 4 independent waves; no loop, no barriers. V reads now use the padded
// VSTR stride (breaks L1-set/L2-channel aliasing).
// ---------------------------------------------------------------------------
__global__ __launch_bounds__(256) void attn_phase1(
    const unsigned short* __restrict__ Qbf,
    const unsigned short* __restrict__ Kbf,
    const unsigned short* __restrict__ Vt,
    float* __restrict__ P2)
{
    __shared__ unsigned int Pbuf[4][16][68];   // 17.4 KB

    int r = blockIdx.x;
    int qt = 0;
    while (r >= (qt >> 1) + 1) { r -= (qt >> 1) + 1; ++qt; }
    const int cch  = r;
    const int b    = blockIdx.y;
    const int i0   = qt << 6;
    const int j0   = cch << 7;

    const int tid  = threadIdx.x;
    const int wv   = tid >> 6;
    const int lane = tid & 63;
    const int q    = lane >> 4;
    const int n    = lane & 15;
    const int wrow0 = i0 + wv * 16;
    const int irow  = wrow0 + n;

    const unsigned short* Qp = Qbf + (size_t)b * T_SEQ * H;
    const unsigned short* Kp = Kbf + (size_t)b * T_SEQ * H;
    const unsigned short* vrow = Vt + (size_t)b * H * VSTR + (size_t)n * VSTR;

    short8_t qf = {0,0,0,0,0,0,0,0};
    if (q < 2)
        qf = *reinterpret_cast<const short8_t*>(Qp + (size_t)irow * H + q * 8);

    // 8 S-MFMAs; K loads batched (full memory-level parallelism).
    f32x4 S[8];
#pragma unroll
    for (int s = 0; s < 8; ++s) {
        short8_t kf = {0,0,0,0,0,0,0,0};
        if (q < 2)
            kf = *reinterpret_cast<const short8_t*>(
                    Kp + (size_t)(j0 + s * 16 + n) * H + q * 8);
        f32x4 z = {0.f, 0.f, 0.f, 0.f};
        S[s] = __builtin_amdgcn_mfma_f32_16x16x32_bf16(kf, qf, z, 0, 0, 0);
    }
    // V fragments issued early (consumed only after softmax).
    short8_t vf[4];
#pragma unroll
    for (int h = 0; h < 4; ++h)
        vf[h] = *reinterpret_cast<const short8_t*>(vrow + j0 + h * 32 + q * 8);

    // Causal mask only for the diagonal chunk (wave-uniform test) + row max.
    float tm = -1e30f;
    if (j0 + 127 > wrow0) {
#pragma unroll
        for (int s = 0; s < 8; ++s) {
            const int kb = j0 + s * 16 + q * 4;
#pragma unroll
            for (int rr = 0; rr < 4; ++rr) {
                float v = (kb + rr <= irow) ? S[s][rr] : -1e30f;
                S[s][rr] = v;
                tm = fmaxf(tm, v);
            }
        }
    } else {
#pragma unroll
        for (int s = 0; s < 8; ++s)
            tm = fmaxf(tm, fmaxf(fmaxf(S[s][0], S[s][1]),
                                 fmaxf(S[s][2], S[s][3])));
    }
    tm = fmaxf(tm, __shfl_xor(tm, 16));
    tm = fmaxf(tm, __shfl_xor(tm, 32));
    const float m = tm;

    // exp2, per-quad partial sum, pack P^T into LDS.
    float l = 0.f;
#pragma unroll
    for (int s = 0; s < 8; ++s) {
        float e0 = EXP2F(S[s][0] - m);
        float e1 = EXP2F(S[s][1] - m);
        float e2 = EXP2F(S[s][2] - m);
        float e3 = EXP2F(S[s][3] - m);
        l += (e0 + e1) + (e2 + e3);
        unsigned int b0 = __builtin_bit_cast(unsigned int, e0);
        unsigned int b1 = __builtin_bit_cast(unsigned int, e1);
        unsigned int b2 = __builtin_bit_cast(unsigned int, e2);
        unsigned int b3 = __builtin_bit_cast(unsigned int, e3);
        unsigned long long pw =
            (unsigned long long)((b1 & 0xffff0000u) | (b0 >> 16)) |
            ((unsigned long long)((b3 & 0xffff0000u) | (b2 >> 16)) << 32);
        *reinterpret_cast<unsigned long long*>(&Pbuf[wv][n][8 * s + 2 * q]) = pw;
    }

    // PV: O^T = V^T · P^T (4 MFMAs, b128 Pbuf reads).
    f32x4 acc = {0.f, 0.f, 0.f, 0.f};
#pragma unroll
    for (int h = 0; h < 4; ++h) {
        uint4 p4 = *reinterpret_cast<const uint4*>(&Pbuf[wv][n][16 * h + 4 * q]);
        union { uint4 u; short8_t v; } pu; pu.u = p4;
        acc = __builtin_amdgcn_mfma_f32_16x16x32_bf16(vf[h], pu.v, acc, 0, 0, 0);
    }

    l += __shfl_xor(l, 16);
    l += __shfl_xor(l, 32);

    float* pp = P2 + ((size_t)(b * T_SEQ + irow) * MAXP + cch) * 18;
    float2 r01; r01.x = acc[0]; r01.y = acc[1];
    float2 r23; r23.x = acc[2]; r23.y = acc[3];
    *reinterpret_cast<float2*>(pp + q * 4)     = r01;
    *reinterpret_cast<float2*>(pp + q * 4 + 2) = r23;
    if (q == 0) { pp[16] = m; pp[17] = l; }
}

// ---------------------------------------------------------------------------
// Kernel 2b: combine partials (log2 domain), BRANCHLESS FULL UNROLL (r11):
// all 16 slots are loaded unconditionally (allocated; poison is finite),
// validity enforced via select -> exp2(-1e30-M)=0 exactly zeroes invalid
// contributions (0 x finite = 0). All loads issue up front: ~2 latency
// exposures instead of ~25 serial ones.
// ---------------------------------------------------------------------------
__global__ __launch_bounds__(256) void attn_phase2(
    const float* __restrict__ P2, float* __restrict__ out)
{
    const int gid = blockIdx.x * 256 + threadIdx.x;
    const int row = gid >> 4;
    const int d   = gid & 15;
    const int ib  = row & (T_SEQ - 1);
    const int nc  = (ib >> 7) + 1;             // valid chunks for this row
    const float* base = P2 + (size_t)row * (MAXP * 18);

    float mv[MAXP];
#pragma unroll
    for (int p = 0; p < MAXP; ++p) {
        const float raw = base[p * 18 + 16];
        mv[p] = (p < nc) ? raw : -1e30f;
    }
    float M = -1e30f;
#pragma unroll
    for (int p = 0; p < MAXP; ++p) M = fmaxf(M, mv[p]);

    float L = 0.f, o = 0.f;
#pragma unroll
    for (int p = 0; p < MAXP; ++p) {
        const float wgt = EXP2F(mv[p] - M);    // 0 for invalid slots
        L += wgt * base[p * 18 + 17];
        o += wgt * base[p * 18 + d];
    }
    out[gid] = o / L;
}

// ---------------------------------------------------------------------------
extern "C" void kernel_launch(void* const* d_in, const int* in_sizes, int n_in,
                              void* d_out, int out_size, void* d_ws, size_t ws_size,
                              hipStream_t stream)
{
    const float* x  = (const float*)d_in[0];
    const float* Wq = (const float*)d_in[1];
    const float* Wk = (const float*)d_in[2];
    const float* Wv = (const float*)d_in[3];
    float* out = (float*)d_out;

    const size_t NE = (size_t)BATCH * T_SEQ * H;      // 262144 elems per buf
    unsigned short* Qbf = (unsigned short*)d_ws;
    unsigned short* Kbf = Qbf + NE;
    unsigned short* Vt  = Kbf + NE;
    // Vt padded: BATCH * H * VSTR elems (even count -> float alignment ok)
    float* P2 = (float*)(Vt + (size_t)BATCH * H * VSTR);

    qkv_kernel<<<BATCH * T_SEQ / 64, 256, 0, stream>>>(
        x, Wq, Wk, Wv, Qbf, Kbf, Vt);
    attn_phase1<<<dim3(272, BATCH), 256, 0, stream>>>(Qbf, Kbf, Vt, P2);
    attn_phase2<<<(int)(NE / 256), 256, 0, stream>>>(P2, out);
}